// Round 6
// baseline (108.132 us; speedup 1.0000x reference)
//
#include <hip/hip_runtime.h>

#define N 32768
#define P 8192
#define MX 8                          // x-values per wave (wave-uniform)
#define XG 2                          // x-groups per block
#define PH 2                          // pattern halves
#define THREADS (XG * PH * 64)        // 256
#define XPB (XG * MX)                 // 16 x per block
#define NBLK (N / XPB)                // 2048
#define PATS_PER_PH (P / PH)          // 4096 patterns per half
#define QITERS (PATS_PER_PH / 2)      // 2048 pattern-pairs per half
#define ITERS (QITERS / 64)           // 32 (power of 2 — wrap prefetch)

// f = log2(e)/(2*sigma^2), sigma^2 = 1.44; per-x |x|^2 cancels in num/den.
#define RBF_F 0.50093577808645257f

static __device__ __forceinline__ float fast_exp2(float x) {
#if __has_builtin(__builtin_amdgcn_exp2f)
    return __builtin_amdgcn_exp2f(x);
#else
    return exp2f(x);
#endif
}

// exp2 on the MAIN VALU pipe (no trans): magic-number range reduction.
// t in [-42, 0]. n = round(t) via add of 1.5*2^23; f = t-n in [-0.5,0.5];
// deg-4 Taylor (max rel err ~4e-5); scale 2^n built from exponent bits.
static __device__ __forceinline__ float exp2_poly(float t) {
    float u = t + 12582912.0f;              // v_add_f32 (RNE -> round(t))
    int   iu = __float_as_int(u);
    float r = u - 12582912.0f;              // v_sub_f32 (exact)
    float f = t - r;                        // v_sub_f32 (exact)
    float p = fmaf(f, 0.00961812910f, 0.05550410866f);
    p = fmaf(f, p, 0.24022650696f);
    p = fmaf(f, p, 0.69314718056f);
    p = fmaf(f, p, 1.0f);                   // 4x v_fma_f32
    float s = __int_as_float((int)(((unsigned)iu << 23) + 0x3F800000u)); // v_lshl_add_u32
    return p * s;                           // v_mul_f32
}

// c[i] = { 2f*p0, 2f*p1, -f*|p|^2, w }
__global__ void prep_kernel(const float* __restrict__ pat,
                            const float* __restrict__ w2,
                            float4* __restrict__ c) {
    int i = blockIdx.x * blockDim.x + threadIdx.x;
    if (i < P) {
        float p0 = pat[2 * i];
        float p1 = pat[2 * i + 1];
        float4 v;
        v.x = 2.0f * RBF_F * p0;
        v.y = 2.0f * RBF_F * p1;
        v.z = -RBF_F * (p0 * p0 + p1 * p1);
        v.w = w2[i];
        c[i] = v;
    }
}

__global__ __launch_bounds__(THREADS) void
rbf_kernel(const float* __restrict__ X,
           const float4* __restrict__ c,
           float* __restrict__ out) {
    const int t    = threadIdx.x;
    const int lane = t & 63;
    const int w    = __builtin_amdgcn_readfirstlane(t >> 6);  // 0..3
    const int xg   = w >> 1;
    const int ph   = w & 1;

    // 8 wave-uniform x-values (compiler keeps these in SGPRs)
    const int xb = blockIdx.x * XPB + xg * MX;
    const float2* Xp = (const float2*)X;
    float x0[MX], x1[MX];
#pragma unroll
    for (int i = 0; i < MX; ++i) {
        float2 xv = Xp[xb + i];
        x0[i] = xv.x;
        x1[i] = xv.y;
    }

    float num[MX], den[MX];
#pragma unroll
    for (int i = 0; i < MX; ++i) { num[i] = 0.f; den[i] = 0.f; }

    // this wave's pattern stream: 2 consecutive patterns per lane per iter
    const float4* __restrict__ C4 = c + (size_t)ph * PATS_PER_PH;

    float4 a = C4[2 * lane];
    float4 b = C4[2 * lane + 1];

    for (int j = 0; j < ITERS; ++j) {
        // branch-free wrapped prefetch of next iteration's patterns
        const int qn = (((j + 1) & (ITERS - 1)) << 6) + lane;
        float4 an = C4[2 * qn];
        float4 bn = C4[2 * qn + 1];

#pragma unroll
        for (int i = 0; i < MX; ++i) {
            float ta = fmaf(a.y, x1[i], fmaf(a.x, x0[i], a.z));
            float tb = fmaf(b.y, x1[i], fmaf(b.x, x0[i], b.z));
            float ka, kb;
            if ((i & 3) == 3) {          // 1/4 of cells: main-VALU poly exp2
                ka = exp2_poly(ta);
                kb = exp2_poly(tb);
            } else {                     // 3/4 of cells: trans-pipe exp2
                ka = fast_exp2(ta);
                kb = fast_exp2(tb);
            }
            den[i] += ka;
            num[i] = fmaf(ka, a.w, num[i]);
            den[i] += kb;
            num[i] = fmaf(kb, b.w, num[i]);
        }
        a = an;
        b = bn;
    }

    // 6-step butterfly reduction across the wave (pattern partials)
#pragma unroll
    for (int m = 1; m < 64; m <<= 1) {
#pragma unroll
        for (int i = 0; i < MX; ++i) {
            num[i] += __shfl_xor(num[i], m, 64);
            den[i] += __shfl_xor(den[i], m, 64);
        }
    }

    __shared__ float red[XG][PH][MX][2];
    if (lane == 0) {
#pragma unroll
        for (int i = 0; i < MX; ++i) {
            red[xg][ph][i][0] = num[i];
            red[xg][ph][i][1] = den[i];
        }
    }
    __syncthreads();

    if (t < XPB) {
        int g = t >> 3, xi = t & 7;
        float nn = red[g][0][xi][0] + red[g][1][xi][0];
        float dd = red[g][0][xi][1] + red[g][1][xi][1];
        out[blockIdx.x * XPB + t] = nn / dd;
    }
}

extern "C" void kernel_launch(void* const* d_in, const int* in_sizes, int n_in,
                              void* d_out, int out_size, void* d_ws, size_t ws_size,
                              hipStream_t stream) {
    const float* X   = (const float*)d_in[0];   // [32768, 2]
    const float* pat = (const float*)d_in[1];   // [8192, 2]
    const float* w2  = (const float*)d_in[2];   // [8192]
    float* out = (float*)d_out;                 // [32768]
    float4* c = (float4*)d_ws;                  // 8192 * 16 B = 128 KB

    prep_kernel<<<(P + 255) / 256, 256, 0, stream>>>(pat, w2, c);
    rbf_kernel<<<NBLK, THREADS, 0, stream>>>(X, c, out);
}

// Round 7
// 98.581 us; speedup vs baseline: 1.0969x; 1.0969x over previous
//
#include <hip/hip_runtime.h>

#define N 32768
#define P 8192
#define MX 8                          // x-values per wave (wave-uniform)
#define XG 2                          // x-groups per block
#define PH 2                          // pattern halves
#define THREADS (XG * PH * 64)        // 256
#define XPB (XG * MX)                 // 16 x per block
#define NBLK (N / XPB)                // 2048
#define PATS_PER_PH (P / PH)          // 4096 patterns per half
#define ITERS (PATS_PER_PH / 128)     // 32 chunks of 128 patterns (2/lane)

// f = log2(e)/(2*sigma^2), sigma^2 = 1.44; per-x |x|^2 cancels in num/den.
#define RBF_F 0.50093577808645257f

typedef _Float16 h2 __attribute__((ext_vector_type(2)));

static __device__ __forceinline__ float fast_exp2(float x) {
#if __has_builtin(__builtin_amdgcn_exp2f)
    return __builtin_amdgcn_exp2f(x);
#else
    return exp2f(x);
#endif
}

// One-op 2D dot on the main VALU: t = c01.x*xh.x + c01.y*xh.y + c2
static __device__ __forceinline__ float dot2(float c01, h2 xh, float c2) {
#if __has_builtin(__builtin_amdgcn_fdot2)
    return __builtin_amdgcn_fdot2(__builtin_bit_cast(h2, c01), xh, c2, false);
#else
    h2 cc = __builtin_bit_cast(h2, c01);
    return fmaf((float)cc.x, (float)xh.x, fmaf((float)cc.y, (float)xh.y, c2));
#endif
}

// c[i] = { bitcast(h2{2f*p0, 2f*p1}), -f*|p|^2 (f32), w (f32), pad }
__global__ void prep_kernel(const float* __restrict__ pat,
                            const float* __restrict__ w2,
                            float4* __restrict__ c) {
    int i = blockIdx.x * blockDim.x + threadIdx.x;
    if (i < P) {
        float p0 = pat[2 * i];
        float p1 = pat[2 * i + 1];
        h2 hh;
        hh.x = (_Float16)(2.0f * RBF_F * p0);
        hh.y = (_Float16)(2.0f * RBF_F * p1);
        float4 v;
        v.x = __builtin_bit_cast(float, hh);
        v.y = -RBF_F * (p0 * p0 + p1 * p1);
        v.z = w2[i];
        v.w = 0.0f;
        c[i] = v;
    }
}

__global__ __launch_bounds__(THREADS) void
rbf_kernel(const float* __restrict__ X,
           const float4* __restrict__ c,
           float* __restrict__ out) {
    const int t    = threadIdx.x;
    const int lane = t & 63;
    const int w    = __builtin_amdgcn_readfirstlane(t >> 6);  // 0..3
    const int xg   = w >> 1;
    const int ph   = w & 1;

    // 8 wave-uniform x-values as packed f16 pairs (1 VGPR each)
    const int xb = blockIdx.x * XPB + xg * MX;
    const float2* Xp = (const float2*)X;
    h2 xh[MX];
#pragma unroll
    for (int i = 0; i < MX; ++i) {
        float2 xv = Xp[xb + i];
        h2 hv;
        hv.x = (_Float16)xv.x;
        hv.y = (_Float16)xv.y;
        xh[i] = hv;
    }

    float num[MX], den[MX];
#pragma unroll
    for (int i = 0; i < MX; ++i) { num[i] = 0.f; den[i] = 0.f; }

    // this wave's pattern stream: chunk j = 128 patterns, 2 per lane
    const float4* __restrict__ C4 = c + (size_t)ph * PATS_PER_PH;

    auto compute = [&](const float4& A, const float4& B) {
#pragma unroll
        for (int i = 0; i < MX; ++i) {
            float ta = dot2(A.x, xh[i], A.y);
            float tb = dot2(B.x, xh[i], B.y);
            float ka = fast_exp2(ta);
            float kb = fast_exp2(tb);
            den[i] += ka;
            num[i] = fmaf(ka, A.z, num[i]);
            den[i] += kb;
            num[i] = fmaf(kb, B.z, num[i]);
        }
    };

    // depth-2 software pipeline, hand-unrolled x2 (SSA renaming, no copies)
    float4 a0 = C4[(0 << 7) + 2 * lane];
    float4 b0 = C4[(0 << 7) + 2 * lane + 1];
    float4 a1 = C4[(1 << 7) + 2 * lane];
    float4 b1 = C4[(1 << 7) + 2 * lane + 1];

    for (int j = 0; j < ITERS; j += 2) {
        {
            const int j2 = (j + 2) & (ITERS - 1);
            float4 na = C4[(j2 << 7) + 2 * lane];
            float4 nb = C4[(j2 << 7) + 2 * lane + 1];
            compute(a0, b0);
            a0 = na; b0 = nb;
        }
        {
            const int j3 = (j + 3) & (ITERS - 1);
            float4 na = C4[(j3 << 7) + 2 * lane];
            float4 nb = C4[(j3 << 7) + 2 * lane + 1];
            compute(a1, b1);
            a1 = na; b1 = nb;
        }
    }

    // 6-step butterfly reduction across the wave (pattern partials)
#pragma unroll
    for (int m = 1; m < 64; m <<= 1) {
#pragma unroll
        for (int i = 0; i < MX; ++i) {
            num[i] += __shfl_xor(num[i], m, 64);
            den[i] += __shfl_xor(den[i], m, 64);
        }
    }

    __shared__ float red[XG][PH][MX][2];
    if (lane == 0) {
#pragma unroll
        for (int i = 0; i < MX; ++i) {
            red[xg][ph][i][0] = num[i];
            red[xg][ph][i][1] = den[i];
        }
    }
    __syncthreads();

    if (t < XPB) {
        int g = t >> 3, xi = t & 7;
        float nn = red[g][0][xi][0] + red[g][1][xi][0];
        float dd = red[g][0][xi][1] + red[g][1][xi][1];
        out[blockIdx.x * XPB + t] = nn / dd;
    }
}

extern "C" void kernel_launch(void* const* d_in, const int* in_sizes, int n_in,
                              void* d_out, int out_size, void* d_ws, size_t ws_size,
                              hipStream_t stream) {
    const float* X   = (const float*)d_in[0];   // [32768, 2]
    const float* pat = (const float*)d_in[1];   // [8192, 2]
    const float* w2  = (const float*)d_in[2];   // [8192]
    float* out = (float*)d_out;                 // [32768]
    float4* c = (float4*)d_ws;                  // 8192 * 16 B = 128 KB

    prep_kernel<<<(P + 255) / 256, 256, 0, stream>>>(pat, w2, c);
    rbf_kernel<<<NBLK, THREADS, 0, stream>>>(X, c, out);
}